// Round 1
// baseline (180.658 us; speedup 1.0000x reference)
//
#include <hip/hip_runtime.h>
#include <cfloat>
#include <stdint.h>

#define B_   16
#define N_   2048
#define KK   10          // window = K+1
#define H_   128
#define SUB  32          // chunk size
#define NCH  (N_ / SUB)  // 64 chunks

#define RANK_BLOCKS (B_ * 16)                  // 16 segs/batch, 128 elems/seg, E=2/thread
#define WEFF_ELEMS  (H_ * KK * 2 + H_)         // 2688
#define WEFF_BLOCKS ((WEFF_ELEMS + 63) / 64)   // 42

__device__ inline uint32_t f32_ordered(float f) {
    uint32_t u = __float_as_uint(f);
    return (u & 0x80000000u) ? ~u : (u | 0x80000000u);
}

// ---- fused setup, v2: rank-by-count sort (replaces 66-pass bitonic).
// Keys (ordered_x<<32 | idx) are unique, so rank(i) = #"{j : key_j < key_i}" is
// an exact permutation and yields the SAME ascending array the bitonic sort
// produced. 256 rank blocks x 64 threads (vs 16 blocks before): full-chip
// parallel, no per-pass barriers. Each thread ranks 2 elements against the
// 2048-key LDS image (b128 broadcast reads, 2 keys/read amortized over both
// elements -> balanced VALU/LDS at ~16K cyc/wave).
// Blocks >= RANK_BLOCKS precompute weff/btot (same arithmetic as before).
__global__ __launch_bounds__(64) void setup_kernel(
    const float* __restrict__ x,
    const float* __restrict__ Wconv, const float* __restrict__ bconv,
    const float* __restrict__ b1,    const float* __restrict__ W2,
    const float* __restrict__ b2,
    float4* __restrict__ xsorted,    // [B][N] (px,py,sm,orig_idx_bits)
    float*  __restrict__ weff,       // [H*20]
    float*  __restrict__ btot)       // [H]
{
#pragma clang fp contract(off)
    __shared__ __align__(16) uint64_t sk[N_];
    const int tid = threadIdx.x;

    if (blockIdx.x >= RANK_BLOCKS) {
        int gid = (blockIdx.x - RANK_BLOCKS) * 64 + tid;
        if (gid < H_ * KK * 2) {
            int e = gid / 20, r = gid % 20, k = r >> 1, c = r & 1;
            float acc = 0.f;
            for (int h = 0; h < H_; ++h)
                acc += W2[e * H_ + h] * Wconv[h * (2 * KK) + c * KK + k];
            weff[gid] = acc;
        } else if (gid < H_ * KK * 2 + H_) {
            int e = gid - H_ * KK * 2;
            float acc = b1[e] + b2[e];
            for (int h = 0; h < H_; ++h) acc += W2[e * H_ + h] * bconv[h];
            btot[e] = acc;
        }
        return;
    }

    const int b   = blockIdx.x >> 4;   // 16 seg-blocks per batch
    const int seg = blockIdx.x & 15;
    const float2* xb = (const float2*)(x + (size_t)b * N_ * 2);

    // stage all 2048 keys of this batch in LDS
    for (int i = tid; i < N_; i += 64)
        sk[i] = ((uint64_t)f32_ordered(xb[i].x) << 32) | (uint32_t)i;
    __syncthreads();

    // rank two owned elements by counting strictly-smaller keys
    const int i0 = seg * 128 + tid;
    const int i1 = i0 + 64;
    const uint64_t k0 = sk[i0];
    const uint64_t k1 = sk[i1];
    int r0 = 0, r1 = 0;
    const ulonglong2* sk2 = (const ulonglong2*)sk;
#pragma unroll 8
    for (int j = 0; j < N_ / 2; ++j) {
        ulonglong2 kk = sk2[j];          // ds_read_b128 broadcast: 2 keys
        r0 += (int)(kk.x < k0) + (int)(kk.y < k0);
        r1 += (int)(kk.x < k1) + (int)(kk.y < k1);
    }

    float2 p0 = xb[i0];
    float2 p1 = xb[i1];
    float sm0 = p0.x * p0.x + p0.y * p0.y;   // no FMA (np sum convention)
    float sm1 = p1.x * p1.x + p1.y * p1.y;
    xsorted[(size_t)b * N_ + r0] =
        make_float4(p0.x, p0.y, sm0, __uint_as_float((uint32_t)i0));
    xsorted[(size_t)b * N_ + r1] =
        make_float4(p1.x, p1.y, sm1, __uint_as_float((uint32_t)i1));
}

// ---- main kernel: 512 threads = 8 waves per 64 sorted queries.
// wave w owns chunks c == w (mod 8); phase1 = nearest owned chunk
// (the 8 waves' nearest chunks tile the tile's neighborhood), phase2 =
// outward two-pointer expansion with conservative x-gap termination.
__global__ __launch_bounds__(512, 4) void knn_conv_kernel(
    const float4* __restrict__ xsorted,
    const float* __restrict__ W1,
    const float* __restrict__ weff,
    const float* __restrict__ btot,
    float* __restrict__ out)
{
#pragma clang fp contract(off)
    __shared__ float4   xs4[N_];          // 32 KB
    __shared__ uint64_t mkeys[64 * 81];   // 40.5 KB
    __shared__ float    wcoord[64 * 21];  //  5.25 KB

    const int tid  = threadIdx.x;
    const int w    = tid >> 6;
    const int l    = tid & 63;
    const int b    = blockIdx.x >> 5;
    const int tile = blockIdx.x & 31;

    const float4* xb = xsorted + (size_t)b * N_;
    for (int i = tid; i < N_; i += 512) xs4[i] = xb[i];
    __syncthreads();

    const int    n  = tile * 64 + l;
    const float4 qv = xs4[n];
    const float  qx = qv.x, qy = qv.y, sqn = qv.z;
    const float  qa  = xs4[tile * 64].x;       // tile x-range (uniform)
    const float  qbx = xs4[tile * 64 + 63].x;

    // sorted-10 of u64 keys: (d2_bits<<32)|(orig_idx<<11)|sorted_pos.
    const uint64_t KINIT = (((uint64_t)0x7F7FFFFFu) << 32) | 0x3FFFFFu; // FLT_MAX d2
    uint64_t hk[KK];
#pragma unroll
    for (int j = 0; j < KK; ++j) hk[j] = KINIT;
    float h9d = FLT_MAX;   // d2 field of hk[9] as float (cheap guard)

    auto scan_chunk = [&](int mc) {
        for (int mm = 0; mm < SUB; ++mm) {
            const int m = mc + mm;               // wave-uniform -> broadcast
            float4 c4 = xs4[m];
            float s  = sqn + c4.z;
            float pr = qx * c4.x;                        // rn(qx*px)
            float dt = __builtin_fmaf(qy, c4.y, pr);     // fma accumulate (np)
            float d2 = __builtin_fmaf(-2.0f, dt, s);     // rn(s - 2*dot)
            float dc = d2 > 0.0f ? d2 : 0.0f;
            if (dc <= h9d) {                     // <= so exact ties enter
                uint32_t oi = __float_as_uint(c4.w);
                uint64_t key = ((uint64_t)__float_as_uint(dc) << 32)
                             | (oi << 11) | (uint32_t)m;
                if (key < hk[KK - 1]) {
#pragma unroll
                    for (int j = KK - 1; j >= 1; --j) {
                        bool cj  = key < hk[j];
                        bool cjm = key < hk[j - 1];
                        hk[j] = cj ? (cjm ? hk[j - 1] : key) : hk[j];
                    }
                    hk[0] = (key < hk[0]) ? key : hk[0];
                }
                h9d = __uint_as_float((uint32_t)(hk[KK - 1] >> 32));
            }
        }
    };

    // phase 1: nearest owned chunk (unconditional; seeds a tight bound)
    const int ct2 = 2 * tile;
    const int a   = (w - ct2) & 7;
    const int c1  = ct2 + a;
    const int c2  = c1 - 8;
    int c_near = (a <= 4) ? c1 : c2;
    if (c1 > NCH - 1) c_near = c2;
    if (c2 < 0)       c_near = c1;
    scan_chunk(c_near * SUB);

    // phase 2: two-pointer outward expansion; gaps monotone per side, so a
    // failed skip test kills that side for good. Control flow wave-uniform.
    int  cl = c_near - 8, cr = c_near + 8;
    bool la = (cl >= 0), ra = (cr <= NCH - 1);
    while (la || ra) {
        float wm = h9d;                       // wave-max of 10th-best d2
        wm = fmaxf(wm, __shfl_xor(wm, 1,  64));
        wm = fmaxf(wm, __shfl_xor(wm, 2,  64));
        wm = fmaxf(wm, __shfl_xor(wm, 4,  64));
        wm = fmaxf(wm, __shfl_xor(wm, 8,  64));
        wm = fmaxf(wm, __shfl_xor(wm, 16, 64));
        wm = fmaxf(wm, __shfl_xor(wm, 32, 64));
        float gl = la ? (qa - xs4[cl * SUB + SUB - 1].x) : FLT_MAX;  // >= 0
        float gr = ra ? (xs4[cr * SUB].x - qbx)          : FLT_MAX;  // >= 0
        bool pickL = la && (!ra || gl <= gr);
        if (pickL) {
            if (__builtin_fmaf(gl, gl, -4e-6f) > wm) la = false;  // margin >> f32 d2 err
            else { scan_chunk(cl * SUB); cl -= 8; la = (cl >= 0); }
        } else {
            if (__builtin_fmaf(gr, gr, -4e-6f) > wm) ra = false;
            else { scan_chunk(cr * SUB); cr += 8; ra = (cr <= NCH - 1); }
        }
    }

    // publish partial lists
    {
        const int mb = l * 81 + w * 10;
#pragma unroll
        for (int j = 0; j < KK; ++j) mkeys[mb + j] = hk[j];
    }

    // hoist epilogue weights (latency overlaps the barrier)
    const int e = tid & 127;
    float we[20];
    {
        const float4* wp = (const float4*)(weff + e * 20);
#pragma unroll
        for (int r = 0; r < 5; ++r) {
            float4 v = wp[r];
            we[4 * r + 0] = v.x; we[4 * r + 1] = v.y;
            we[4 * r + 2] = v.z; we[4 * r + 3] = v.w;
        }
    }
    const float w1x = W1[e * 2 + 0];
    const float w1y = W1[e * 2 + 1];
    const float bt  = btot[e];
    __syncthreads();

    // parallel merge: 8 lanes per query (q = tid>>3, r = tid&7), groups of 8
    // aligned within a wave -> shfl_xor masks 1/2/4 stay in-group. Keys are
    // unique (pos field), so exactly one winner per selection.
    {
        const int q = tid >> 3;
        const int r = tid & 7;
        const int mb = q * 81 + r * 10;
        int p = 0;
#pragma unroll
        for (int sel = 0; sel < KK; ++sel) {
            uint64_t v = (p < KK) ? mkeys[mb + p] : 0xFFFFFFFFFFFFFFFFull;
            uint64_t t1 = __shfl_xor((unsigned long long)v, 1, 64);
            uint64_t m1 = v  < t1 ? v  : t1;
            uint64_t t2 = __shfl_xor((unsigned long long)m1, 2, 64);
            uint64_t m2 = m1 < t2 ? m1 : t2;
            uint64_t t4 = __shfl_xor((unsigned long long)m2, 4, 64);
            uint64_t vm = m2 < t4 ? m2 : t4;
            if (v == vm) {
                ++p;
                float4 c = xs4[(int)(vm & 0x7FF)];
                const int k = (KK - 1) - sel;          // flip: nearest -> k=9
                wcoord[q * 21 + 2 * k + 0] = c.x;
                wcoord[q * 21 + 2 * k + 1] = c.y;
            }
        }
    }
    __syncthreads();

    // epilogue: thread -> channel e; rows scattered to ORIGINAL indices
    // (128 consecutive floats per row, coalesced per wave-store).
    const int qb_ = tid >> 7;
    const size_t obase = (size_t)b * N_ * H_;
#pragma unroll
    for (int jj = 0; jj < 16; ++jj) {
        const int qq = qb_ + 4 * jj;
        float4 xq = xs4[tile * 64 + qq];
        uint32_t orig = __float_as_uint(xq.w);
        const float* wc = &wcoord[qq * 21];
        float acc = bt;
        acc += xq.x * w1x;
        acc += xq.y * w1y;
#pragma unroll
        for (int k = 0; k < KK; ++k) {
            acc += wc[2 * k + 0] * we[2 * k + 0];
            acc += wc[2 * k + 1] * we[2 * k + 1];
        }
        out[obase + (size_t)orig * H_ + e] = acc;
    }
}

extern "C" void kernel_launch(void* const* d_in, const int* in_sizes, int n_in,
                              void* d_out, int out_size, void* d_ws, size_t ws_size,
                              hipStream_t stream) {
    const float* x     = (const float*)d_in[0];
    const float* Wconv = (const float*)d_in[1];
    const float* bconv = (const float*)d_in[2];
    const float* W1    = (const float*)d_in[3];
    const float* b1    = (const float*)d_in[4];
    const float* W2    = (const float*)d_in[5];
    const float* b2    = (const float*)d_in[6];
    float* out  = (float*)d_out;
    float* weff = (float*)d_ws;                           // 2560 floats
    float* btot = weff + H_ * KK * 2;                     // 128 floats
    float4* xsorted = (float4*)((char*)d_ws + 16384);     // 16*2048*16B

    setup_kernel<<<dim3(RANK_BLOCKS + WEFF_BLOCKS), dim3(64), 0, stream>>>(
        x, Wconv, bconv, b1, W2, b2, xsorted, weff, btot);
    knn_conv_kernel<<<dim3(B_ * (N_ / 64)), dim3(512), 0, stream>>>(
        xsorted, W1, weff, btot, out);
}

// Round 2
// 177.530 us; speedup vs baseline: 1.0176x; 1.0176x over previous
//
#include <hip/hip_runtime.h>
#include <cfloat>
#include <stdint.h>

#define B_   16
#define N_   2048
#define KK   10          // window = K+1
#define H_   128
#define SUB  32          // chunk size
#define NCH  (N_ / SUB)  // 64 chunks

#define RANK_BLOCKS (B_ * 16)                  // 16 segs/batch, 128 elems/seg, E=2/thread
#define WEFF_ELEMS  (H_ * KK * 2 + H_)         // 2688
#define WEFF_BLOCKS ((WEFF_ELEMS + 63) / 64)   // 42

__device__ inline uint32_t f32_ordered(float f) {
    uint32_t u = __float_as_uint(f);
    return (u & 0x80000000u) ? ~u : (u | 0x80000000u);
}

// ---- fused setup: rank-by-count sort (O(N^2) compares, barrier-free,
// full-chip parallel). Keys (ordered_x<<32 | idx) are unique, so
// rank(i) = #{j : key_j < key_i} is an exact permutation producing the
// identical ascending array the bitonic sort produced.
__global__ __launch_bounds__(64) void setup_kernel(
    const float* __restrict__ x,
    const float* __restrict__ Wconv, const float* __restrict__ bconv,
    const float* __restrict__ b1,    const float* __restrict__ W2,
    const float* __restrict__ b2,
    float4* __restrict__ xsorted,    // [B][N] (px,py,sm,orig_idx_bits)
    float*  __restrict__ weff,       // [H*20]
    float*  __restrict__ btot)       // [H]
{
#pragma clang fp contract(off)
    __shared__ __align__(16) uint64_t sk[N_];
    const int tid = threadIdx.x;

    if (blockIdx.x >= RANK_BLOCKS) {
        int gid = (blockIdx.x - RANK_BLOCKS) * 64 + tid;
        if (gid < H_ * KK * 2) {
            int e = gid / 20, r = gid % 20, k = r >> 1, c = r & 1;
            float acc = 0.f;
#pragma unroll 8
            for (int h = 0; h < H_; ++h)
                acc += W2[e * H_ + h] * Wconv[h * (2 * KK) + c * KK + k];
            weff[gid] = acc;
        } else if (gid < H_ * KK * 2 + H_) {
            int e = gid - H_ * KK * 2;
            float acc = b1[e] + b2[e];
#pragma unroll 8
            for (int h = 0; h < H_; ++h) acc += W2[e * H_ + h] * bconv[h];
            btot[e] = acc;
        }
        return;
    }

    const int b   = blockIdx.x >> 4;   // 16 seg-blocks per batch
    const int seg = blockIdx.x & 15;
    const float2* xb = (const float2*)(x + (size_t)b * N_ * 2);

    // stage all 2048 keys of this batch in LDS
    for (int i = tid; i < N_; i += 64)
        sk[i] = ((uint64_t)f32_ordered(xb[i].x) << 32) | (uint32_t)i;
    __syncthreads();

    // rank two owned elements by counting strictly-smaller keys
    const int i0 = seg * 128 + tid;
    const int i1 = i0 + 64;
    const uint64_t k0 = sk[i0];
    const uint64_t k1 = sk[i1];
    int r0 = 0, r1 = 0;
    const ulonglong2* sk2 = (const ulonglong2*)sk;
#pragma unroll 8
    for (int j = 0; j < N_ / 2; ++j) {
        ulonglong2 kk = sk2[j];          // ds_read_b128 broadcast: 2 keys
        r0 += (int)(kk.x < k0) + (int)(kk.y < k0);
        r1 += (int)(kk.x < k1) + (int)(kk.y < k1);
    }

    float2 p0 = xb[i0];
    float2 p1 = xb[i1];
    float sm0 = p0.x * p0.x + p0.y * p0.y;   // no FMA (np sum convention)
    float sm1 = p1.x * p1.x + p1.y * p1.y;
    xsorted[(size_t)b * N_ + r0] =
        make_float4(p0.x, p0.y, sm0, __uint_as_float((uint32_t)i0));
    xsorted[(size_t)b * N_ + r1] =
        make_float4(p1.x, p1.y, sm1, __uint_as_float((uint32_t)i1));
}

// ---- main kernel: 512 threads = 8 waves per 64 sorted queries.
// wave w owns chunks c == w (mod 8); phase1 = nearest owned chunk, then a
// CROSS-WAVE bound exchange (min over waves of per-lane 10th-best d2 -> a
// valid upper bound on the true 10th-best), then phase2 = outward
// two-pointer expansion gated by the shared bound.
__global__ __launch_bounds__(512, 4) void knn_conv_kernel(
    const float4* __restrict__ xsorted,
    const float* __restrict__ W1,
    const float* __restrict__ weff,
    const float* __restrict__ btot,
    float* __restrict__ out)
{
#pragma clang fp contract(off)
    __shared__ float4   xs4[N_];          // 32 KB
    __shared__ uint64_t mkeys[64 * 81];   // 40.5 KB
    __shared__ float    wcoord[64 * 21];  //  5.25 KB
    __shared__ float    hbound[8 * 64];   //  2 KB  (per-wave per-lane 10th-best)

    const int tid  = threadIdx.x;
    const int w    = tid >> 6;
    const int l    = tid & 63;
    const int b    = blockIdx.x >> 5;
    const int tile = blockIdx.x & 31;

    const float4* xb = xsorted + (size_t)b * N_;
    for (int i = tid; i < N_; i += 512) xs4[i] = xb[i];
    __syncthreads();

    const int    n  = tile * 64 + l;
    const float4 qv = xs4[n];
    const float  qx = qv.x, qy = qv.y, sqn = qv.z;
    const float  qa  = xs4[tile * 64].x;       // tile x-range (uniform)
    const float  qbx = xs4[tile * 64 + 63].x;

    // sorted-10 of u64 keys: (d2_bits<<32)|(orig_idx<<11)|sorted_pos.
    const uint64_t KINIT = (((uint64_t)0x7F7FFFFFu) << 32) | 0x3FFFFFu; // FLT_MAX d2
    uint64_t hk[KK];
#pragma unroll
    for (int j = 0; j < KK; ++j) hk[j] = KINIT;
    float h9d  = FLT_MAX;   // d2 field of hk[9] (own partial 10th-best)
    float shb  = FLT_MAX;   // shared bound (min over waves, set after phase 1)
    float gate = FLT_MAX;   // fminf(h9d, shb): accept/terminate gate

    auto scan_chunk = [&](int mc) {
        for (int mm = 0; mm < SUB; ++mm) {
            const int m = mc + mm;               // wave-uniform -> broadcast
            float4 c4 = xs4[m];
            float s  = sqn + c4.z;
            float pr = qx * c4.x;                        // rn(qx*px)
            float dt = __builtin_fmaf(qy, c4.y, pr);     // fma accumulate (np)
            float d2 = __builtin_fmaf(-2.0f, dt, s);     // rn(s - 2*dot)
            float dc = d2 > 0.0f ? d2 : 0.0f;
            if (dc <= gate) {                    // <= so exact ties enter
                uint32_t oi = __float_as_uint(c4.w);
                uint64_t key = ((uint64_t)__float_as_uint(dc) << 32)
                             | (oi << 11) | (uint32_t)m;
                if (key < hk[KK - 1]) {
#pragma unroll
                    for (int j = KK - 1; j >= 1; --j) {
                        bool cj  = key < hk[j];
                        bool cjm = key < hk[j - 1];
                        hk[j] = cj ? (cjm ? hk[j - 1] : key) : hk[j];
                    }
                    hk[0] = (key < hk[0]) ? key : hk[0];
                }
                h9d  = __uint_as_float((uint32_t)(hk[KK - 1] >> 32));
                gate = fminf(h9d, shb);
            }
        }
    };

    // phase 1: nearest owned chunk (unconditional; seeds a tight bound)
    const int ct2 = 2 * tile;
    const int a   = (w - ct2) & 7;
    const int c1  = ct2 + a;
    const int c2  = c1 - 8;
    int c_near = (a <= 4) ? c1 : c2;
    if (c1 > NCH - 1) c_near = c2;
    if (c2 < 0)       c_near = c1;
    scan_chunk(c_near * SUB);

    // cross-wave bound exchange: every wave filled 10 real candidates in
    // phase 1, so h9d is a finite upper bound on the true 10th-best for its
    // lane's query. min over waves is still an upper bound -> safe gate for
    // BOTH candidate acceptance and chunk skipping, block-wide.
    hbound[w * 64 + l] = h9d;
    __syncthreads();
    {
        float m0 = fminf(hbound[0 * 64 + l], hbound[1 * 64 + l]);
        float m1 = fminf(hbound[2 * 64 + l], hbound[3 * 64 + l]);
        float m2 = fminf(hbound[4 * 64 + l], hbound[5 * 64 + l]);
        float m3 = fminf(hbound[6 * 64 + l], hbound[7 * 64 + l]);
        shb  = fminf(fminf(m0, m1), fminf(m2, m3));
        gate = fminf(h9d, shb);
    }

    // phase 2: two-pointer outward expansion; gaps monotone per side, so a
    // failed skip test kills that side for good. Control flow wave-uniform.
    int  cl = c_near - 8, cr = c_near + 8;
    bool la = (cl >= 0), ra = (cr <= NCH - 1);
    while (la || ra) {
        float wm = gate;                      // wave-max of gated 10th-best
        wm = fmaxf(wm, __shfl_xor(wm, 1,  64));
        wm = fmaxf(wm, __shfl_xor(wm, 2,  64));
        wm = fmaxf(wm, __shfl_xor(wm, 4,  64));
        wm = fmaxf(wm, __shfl_xor(wm, 8,  64));
        wm = fmaxf(wm, __shfl_xor(wm, 16, 64));
        wm = fmaxf(wm, __shfl_xor(wm, 32, 64));
        float gl = la ? (qa - xs4[cl * SUB + SUB - 1].x) : FLT_MAX;  // >= 0
        float gr = ra ? (xs4[cr * SUB].x - qbx)          : FLT_MAX;  // >= 0
        bool pickL = la && (!ra || gl <= gr);
        if (pickL) {
            if (__builtin_fmaf(gl, gl, -4e-6f) > wm) la = false;  // margin >> f32 d2 err
            else { scan_chunk(cl * SUB); cl -= 8; la = (cl >= 0); }
        } else {
            if (__builtin_fmaf(gr, gr, -4e-6f) > wm) ra = false;
            else { scan_chunk(cr * SUB); cr += 8; ra = (cr <= NCH - 1); }
        }
    }

    // publish partial lists
    {
        const int mb = l * 81 + w * 10;
#pragma unroll
        for (int j = 0; j < KK; ++j) mkeys[mb + j] = hk[j];
    }

    // hoist epilogue weights (latency overlaps the barrier)
    const int e = tid & 127;
    float we[20];
    {
        const float4* wp = (const float4*)(weff + e * 20);
#pragma unroll
        for (int r = 0; r < 5; ++r) {
            float4 v = wp[r];
            we[4 * r + 0] = v.x; we[4 * r + 1] = v.y;
            we[4 * r + 2] = v.z; we[4 * r + 3] = v.w;
        }
    }
    const float w1x = W1[e * 2 + 0];
    const float w1y = W1[e * 2 + 1];
    const float bt  = btot[e];
    __syncthreads();

    // parallel merge: 8 lanes per query (q = tid>>3, r = tid&7), groups of 8
    // aligned within a wave -> shfl_xor masks 1/2/4 stay in-group. Keys are
    // unique (pos field), so exactly one winner per selection. Partial lists
    // may hold gate-excluded junk, but the union provably contains the true
    // top-10 (everything excluded had d2 > an upper bound on the 10th-best).
    {
        const int q = tid >> 3;
        const int r = tid & 7;
        const int mb = q * 81 + r * 10;
        int p = 0;
#pragma unroll
        for (int sel = 0; sel < KK; ++sel) {
            uint64_t v = (p < KK) ? mkeys[mb + p] : 0xFFFFFFFFFFFFFFFFull;
            uint64_t t1 = __shfl_xor((unsigned long long)v, 1, 64);
            uint64_t m1 = v  < t1 ? v  : t1;
            uint64_t t2 = __shfl_xor((unsigned long long)m1, 2, 64);
            uint64_t m2 = m1 < t2 ? m1 : t2;
            uint64_t t4 = __shfl_xor((unsigned long long)m2, 4, 64);
            uint64_t vm = m2 < t4 ? m2 : t4;
            if (v == vm) {
                ++p;
                float4 c = xs4[(int)(vm & 0x7FF)];
                const int k = (KK - 1) - sel;          // flip: nearest -> k=9
                wcoord[q * 21 + 2 * k + 0] = c.x;
                wcoord[q * 21 + 2 * k + 1] = c.y;
            }
        }
    }
    __syncthreads();

    // epilogue: thread -> channel e; rows scattered to ORIGINAL indices
    // (128 consecutive floats per row, coalesced per wave-store).
    const int qb_ = tid >> 7;
    const size_t obase = (size_t)b * N_ * H_;
#pragma unroll
    for (int jj = 0; jj < 16; ++jj) {
        const int qq = qb_ + 4 * jj;
        float4 xq = xs4[tile * 64 + qq];
        uint32_t orig = __float_as_uint(xq.w);
        const float* wc = &wcoord[qq * 21];
        float acc = bt;
        acc += xq.x * w1x;
        acc += xq.y * w1y;
#pragma unroll
        for (int k = 0; k < KK; ++k) {
            acc += wc[2 * k + 0] * we[2 * k + 0];
            acc += wc[2 * k + 1] * we[2 * k + 1];
        }
        out[obase + (size_t)orig * H_ + e] = acc;
    }
}

extern "C" void kernel_launch(void* const* d_in, const int* in_sizes, int n_in,
                              void* d_out, int out_size, void* d_ws, size_t ws_size,
                              hipStream_t stream) {
    const float* x     = (const float*)d_in[0];
    const float* Wconv = (const float*)d_in[1];
    const float* bconv = (const float*)d_in[2];
    const float* W1    = (const float*)d_in[3];
    const float* b1    = (const float*)d_in[4];
    const float* W2    = (const float*)d_in[5];
    const float* b2    = (const float*)d_in[6];
    float* out  = (float*)d_out;
    float* weff = (float*)d_ws;                           // 2560 floats
    float* btot = weff + H_ * KK * 2;                     // 128 floats
    float4* xsorted = (float4*)((char*)d_ws + 16384);     // 16*2048*16B

    setup_kernel<<<dim3(RANK_BLOCKS + WEFF_BLOCKS), dim3(64), 0, stream>>>(
        x, Wconv, bconv, b1, W2, b2, xsorted, weff, btot);
    knn_conv_kernel<<<dim3(B_ * (N_ / 64)), dim3(512), 0, stream>>>(
        xsorted, W1, weff, btot, out);
}

// Round 3
// 143.041 us; speedup vs baseline: 1.2630x; 1.2411x over previous
//
#include <hip/hip_runtime.h>
#include <cfloat>
#include <stdint.h>

#define B_   16
#define N_   2048
#define KK   10          // window = K+1
#define H_   128
#define SUB  32          // chunk size
#define NCH  (N_ / SUB)  // 64 chunks

#define RANK_BLOCKS (B_ * 32)                  // 512: 64-elem segments, 256 thr
#define WEFF_OUT    (H_ * KK * 2 + H_)         // 2688 outputs
#define WEFF_BLOCKS ((WEFF_OUT * 4) / 256)     // 42 (4 lanes/output, exact)

__device__ inline uint32_t f32_ordered(float f) {
    uint32_t u = __float_as_uint(f);
    return (u & 0x80000000u) ? ~u : (u | 0x80000000u);
}

// ---- setup v3: rank-by-count with real TLP+ILP.
// v2 post-mortem: 64-thr blocks = 1 wave/CU and a load->use dependency per
// iteration serialized on ~120cy LDS latency (~50us). v3: 256-thr blocks
// (8 waves/CU), each wave counts a 512-key subrange, 4 ds_read_b128 batched
// per iteration. Keys unchanged -> identical permutation -> identical output.
__global__ __launch_bounds__(256) void setup_kernel(
    const float* __restrict__ x,
    const float* __restrict__ Wconv, const float* __restrict__ bconv,
    const float* __restrict__ b1,    const float* __restrict__ W2,
    const float* __restrict__ b2,
    float4* __restrict__ xsorted,    // [B][N] (px,py,sm,orig_idx_bits)
    float*  __restrict__ weff,       // [H*20]
    float*  __restrict__ btot)       // [H]
{
#pragma clang fp contract(off)
    __shared__ __align__(16) uint64_t sk[N_];   // 16 KB
    __shared__ int pcnt[4 * 64];
    const int tid = threadIdx.x;

    if (blockIdx.x >= RANK_BLOCKS) {
        // weff/btot: 4 lanes per output, 32 MACs each, shfl-reduce.
        const int g = (blockIdx.x - RANK_BLOCKS) * 256 + tid;
        const int o = g >> 2, q = g & 3;
        float acc = 0.f;
        if (o < H_ * KK * 2) {
            const int e = o / 20, r = o % 20, k = r >> 1, c = r & 1;
            const float* w2p = W2 + e * H_ + q * 32;
            const float* wcp = Wconv + (q * 32) * (2 * KK) + c * KK + k;
#pragma unroll 8
            for (int h = 0; h < 32; ++h)
                acc += w2p[h] * wcp[h * (2 * KK)];
        } else {
            const int e = o - H_ * KK * 2;
            const float* w2p = W2 + e * H_ + q * 32;
            const float* bcp = bconv + q * 32;
#pragma unroll 8
            for (int h = 0; h < 32; ++h) acc += w2p[h] * bcp[h];
        }
        acc += __shfl_xor(acc, 1, 64);
        acc += __shfl_xor(acc, 2, 64);
        if (q == 0) {
            if (o < H_ * KK * 2) weff[o] = acc;
            else {
                const int e = o - H_ * KK * 2;
                btot[e] = acc + b1[e] + b2[e];
            }
        }
        return;
    }

    const int b  = blockIdx.x >> 5;   // 32 seg-blocks per batch
    const int sg = blockIdx.x & 31;   // 64-element segment
    const float2* xb = (const float2*)(x + (size_t)b * N_ * 2);

    // stage all 2048 keys of this batch in LDS
    for (int i = tid; i < N_; i += 256)
        sk[i] = ((uint64_t)f32_ordered(xb[i].x) << 32) | (uint32_t)i;
    __syncthreads();

    // wave pt counts keys in [pt*512, pt*512+512) against owned element el
    const int el = tid & 63;
    const int pt = tid >> 6;
    const uint64_t kown = sk[sg * 64 + el];
    const ulonglong2* sk2 = (const ulonglong2*)sk + pt * 256;
    int cnt = 0;
#pragma unroll 2
    for (int j = 0; j < 256; j += 4) {
        ulonglong2 t0 = sk2[j + 0];      // 4 broadcast b128 reads in flight
        ulonglong2 t1 = sk2[j + 1];
        ulonglong2 t2 = sk2[j + 2];
        ulonglong2 t3 = sk2[j + 3];
        cnt += (int)(t0.x < kown) + (int)(t0.y < kown)
             + (int)(t1.x < kown) + (int)(t1.y < kown)
             + (int)(t2.x < kown) + (int)(t2.y < kown)
             + (int)(t3.x < kown) + (int)(t3.y < kown);
    }
    pcnt[pt * 64 + el] = cnt;
    __syncthreads();

    if (tid < 64) {
        const int r = pcnt[tid] + pcnt[64 + tid] + pcnt[128 + tid] + pcnt[192 + tid];
        const int i = sg * 64 + tid;
        float2 p = xb[i];
        float sm = p.x * p.x + p.y * p.y;   // no FMA (np sum convention)
        xsorted[(size_t)b * N_ + r] =
            make_float4(p.x, p.y, sm, __uint_as_float((uint32_t)i));
    }
}

// ---- main kernel: 512 threads = 8 waves per 64 sorted queries.
// wave w owns chunks c == w (mod 8); phase1 = nearest owned chunk, cross-wave
// bound exchange, phase2 = outward two-pointer expansion. Scan loop batches
// 4 candidates per iteration: 4 independent ds_read_b128 + 4 d2s, then the
// (rare) gate-checked inserts -- removes the per-candidate LDS latency chain.
__global__ __launch_bounds__(512, 4) void knn_conv_kernel(
    const float4* __restrict__ xsorted,
    const float* __restrict__ W1,
    const float* __restrict__ weff,
    const float* __restrict__ btot,
    float* __restrict__ out)
{
#pragma clang fp contract(off)
    __shared__ float4   xs4[N_];          // 32 KB
    __shared__ uint64_t mkeys[64 * 81];   // 40.5 KB
    __shared__ float    wcoord[64 * 21];  //  5.25 KB
    __shared__ float    hbound[8 * 64];   //  2 KB

    const int tid  = threadIdx.x;
    const int w    = tid >> 6;
    const int l    = tid & 63;
    const int b    = blockIdx.x >> 5;
    const int tile = blockIdx.x & 31;

    const float4* xb = xsorted + (size_t)b * N_;
    for (int i = tid; i < N_; i += 512) xs4[i] = xb[i];
    __syncthreads();

    const int    n  = tile * 64 + l;
    const float4 qv = xs4[n];
    const float  qx = qv.x, qy = qv.y, sqn = qv.z;
    const float  qa  = xs4[tile * 64].x;       // tile x-range (uniform)
    const float  qbx = xs4[tile * 64 + 63].x;

    // sorted-10 of u64 keys: (d2_bits<<32)|(orig_idx<<11)|sorted_pos.
    const uint64_t KINIT = (((uint64_t)0x7F7FFFFFu) << 32) | 0x3FFFFFu; // FLT_MAX d2
    uint64_t hk[KK];
#pragma unroll
    for (int j = 0; j < KK; ++j) hk[j] = KINIT;
    float h9d  = FLT_MAX;   // d2 field of hk[9] (own partial 10th-best)
    float shb  = FLT_MAX;   // shared bound (min over waves, set after phase 1)
    float gate = FLT_MAX;   // fminf(h9d, shb)

    auto insert = [&](float dc, float cw, int m) {
        uint32_t oi = __float_as_uint(cw);
        uint64_t key = ((uint64_t)__float_as_uint(dc) << 32)
                     | (oi << 11) | (uint32_t)m;
        if (key < hk[KK - 1]) {
#pragma unroll
            for (int j = KK - 1; j >= 1; --j) {
                bool cj  = key < hk[j];
                bool cjm = key < hk[j - 1];
                hk[j] = cj ? (cjm ? hk[j - 1] : key) : hk[j];
            }
            hk[0] = (key < hk[0]) ? key : hk[0];
        }
        h9d  = __uint_as_float((uint32_t)(hk[KK - 1] >> 32));
        gate = fminf(h9d, shb);
    };

    auto scan_chunk = [&](int mc) {
        for (int mm = 0; mm < SUB; mm += 4) {
            const int m0 = mc + mm;              // wave-uniform -> broadcast
            float4 c0 = xs4[m0 + 0];
            float4 c1 = xs4[m0 + 1];
            float4 c2 = xs4[m0 + 2];
            float4 c3 = xs4[m0 + 3];
            float dc0, dc1, dc2, dc3;
            { float s = sqn + c0.z; float pr = qx * c0.x;
              float dt = __builtin_fmaf(qy, c0.y, pr);
              float d2 = __builtin_fmaf(-2.0f, dt, s); dc0 = d2 > 0.0f ? d2 : 0.0f; }
            { float s = sqn + c1.z; float pr = qx * c1.x;
              float dt = __builtin_fmaf(qy, c1.y, pr);
              float d2 = __builtin_fmaf(-2.0f, dt, s); dc1 = d2 > 0.0f ? d2 : 0.0f; }
            { float s = sqn + c2.z; float pr = qx * c2.x;
              float dt = __builtin_fmaf(qy, c2.y, pr);
              float d2 = __builtin_fmaf(-2.0f, dt, s); dc2 = d2 > 0.0f ? d2 : 0.0f; }
            { float s = sqn + c3.z; float pr = qx * c3.x;
              float dt = __builtin_fmaf(qy, c3.y, pr);
              float d2 = __builtin_fmaf(-2.0f, dt, s); dc3 = d2 > 0.0f ? d2 : 0.0f; }
            if (dc0 <= gate) insert(dc0, c0.w, m0 + 0);
            if (dc1 <= gate) insert(dc1, c1.w, m0 + 1);
            if (dc2 <= gate) insert(dc2, c2.w, m0 + 2);
            if (dc3 <= gate) insert(dc3, c3.w, m0 + 3);
        }
    };

    // phase 1: nearest owned chunk (unconditional; seeds a tight bound)
    const int ct2 = 2 * tile;
    const int a   = (w - ct2) & 7;
    const int c1_ = ct2 + a;
    const int c2_ = c1_ - 8;
    int c_near = (a <= 4) ? c1_ : c2_;
    if (c1_ > NCH - 1) c_near = c2_;
    if (c2_ < 0)       c_near = c1_;
    scan_chunk(c_near * SUB);

    // cross-wave bound exchange (min over waves of per-lane 10th-best: a
    // valid upper bound on the true 10th-best -> safe block-wide gate).
    hbound[w * 64 + l] = h9d;
    __syncthreads();
    {
        float m0 = fminf(hbound[0 * 64 + l], hbound[1 * 64 + l]);
        float m1 = fminf(hbound[2 * 64 + l], hbound[3 * 64 + l]);
        float m2 = fminf(hbound[4 * 64 + l], hbound[5 * 64 + l]);
        float m3 = fminf(hbound[6 * 64 + l], hbound[7 * 64 + l]);
        shb  = fminf(fminf(m0, m1), fminf(m2, m3));
        gate = fminf(h9d, shb);
    }

    // phase 2: two-pointer outward expansion; wave-uniform control flow.
    int  cl = c_near - 8, cr = c_near + 8;
    bool la = (cl >= 0), ra = (cr <= NCH - 1);
    while (la || ra) {
        float wm = gate;
        wm = fmaxf(wm, __shfl_xor(wm, 1,  64));
        wm = fmaxf(wm, __shfl_xor(wm, 2,  64));
        wm = fmaxf(wm, __shfl_xor(wm, 4,  64));
        wm = fmaxf(wm, __shfl_xor(wm, 8,  64));
        wm = fmaxf(wm, __shfl_xor(wm, 16, 64));
        wm = fmaxf(wm, __shfl_xor(wm, 32, 64));
        float gl = la ? (qa - xs4[cl * SUB + SUB - 1].x) : FLT_MAX;  // >= 0
        float gr = ra ? (xs4[cr * SUB].x - qbx)          : FLT_MAX;  // >= 0
        bool pickL = la && (!ra || gl <= gr);
        if (pickL) {
            if (__builtin_fmaf(gl, gl, -4e-6f) > wm) la = false;  // margin >> f32 d2 err
            else { scan_chunk(cl * SUB); cl -= 8; la = (cl >= 0); }
        } else {
            if (__builtin_fmaf(gr, gr, -4e-6f) > wm) ra = false;
            else { scan_chunk(cr * SUB); cr += 8; ra = (cr <= NCH - 1); }
        }
    }

    // publish partial lists
    {
        const int mb = l * 81 + w * 10;
#pragma unroll
        for (int j = 0; j < KK; ++j) mkeys[mb + j] = hk[j];
    }

    // hoist epilogue weights (latency overlaps the barrier)
    const int e = tid & 127;
    float we[20];
    {
        const float4* wp = (const float4*)(weff + e * 20);
#pragma unroll
        for (int r = 0; r < 5; ++r) {
            float4 v = wp[r];
            we[4 * r + 0] = v.x; we[4 * r + 1] = v.y;
            we[4 * r + 2] = v.z; we[4 * r + 3] = v.w;
        }
    }
    const float w1x = W1[e * 2 + 0];
    const float w1y = W1[e * 2 + 1];
    const float bt  = btot[e];
    __syncthreads();

    // parallel merge: 8 lanes per query; keys unique -> one winner per sel.
    {
        const int q = tid >> 3;
        const int r = tid & 7;
        const int mb = q * 81 + r * 10;
        int p = 0;
#pragma unroll
        for (int sel = 0; sel < KK; ++sel) {
            uint64_t v = (p < KK) ? mkeys[mb + p] : 0xFFFFFFFFFFFFFFFFull;
            uint64_t t1 = __shfl_xor((unsigned long long)v, 1, 64);
            uint64_t m1 = v  < t1 ? v  : t1;
            uint64_t t2 = __shfl_xor((unsigned long long)m1, 2, 64);
            uint64_t m2 = m1 < t2 ? m1 : t2;
            uint64_t t4 = __shfl_xor((unsigned long long)m2, 4, 64);
            uint64_t vm = m2 < t4 ? m2 : t4;
            if (v == vm) {
                ++p;
                float4 c = xs4[(int)(vm & 0x7FF)];
                const int k = (KK - 1) - sel;          // flip: nearest -> k=9
                wcoord[q * 21 + 2 * k + 0] = c.x;
                wcoord[q * 21 + 2 * k + 1] = c.y;
            }
        }
    }
    __syncthreads();

    // epilogue: thread -> channel e; rows scattered to ORIGINAL indices.
    const int qb_ = tid >> 7;
    const size_t obase = (size_t)b * N_ * H_;
#pragma unroll
    for (int jj = 0; jj < 16; ++jj) {
        const int qq = qb_ + 4 * jj;
        float4 xq = xs4[tile * 64 + qq];
        uint32_t orig = __float_as_uint(xq.w);
        const float* wc = &wcoord[qq * 21];
        float acc = bt;
        acc += xq.x * w1x;
        acc += xq.y * w1y;
#pragma unroll
        for (int k = 0; k < KK; ++k) {
            acc += wc[2 * k + 0] * we[2 * k + 0];
            acc += wc[2 * k + 1] * we[2 * k + 1];
        }
        out[obase + (size_t)orig * H_ + e] = acc;
    }
}

extern "C" void kernel_launch(void* const* d_in, const int* in_sizes, int n_in,
                              void* d_out, int out_size, void* d_ws, size_t ws_size,
                              hipStream_t stream) {
    const float* x     = (const float*)d_in[0];
    const float* Wconv = (const float*)d_in[1];
    const float* bconv = (const float*)d_in[2];
    const float* W1    = (const float*)d_in[3];
    const float* b1    = (const float*)d_in[4];
    const float* W2    = (const float*)d_in[5];
    const float* b2    = (const float*)d_in[6];
    float* out  = (float*)d_out;
    float* weff = (float*)d_ws;                           // 2560 floats
    float* btot = weff + H_ * KK * 2;                     // 128 floats
    float4* xsorted = (float4*)((char*)d_ws + 16384);     // 16*2048*16B

    setup_kernel<<<dim3(RANK_BLOCKS + WEFF_BLOCKS), dim3(256), 0, stream>>>(
        x, Wconv, bconv, b1, W2, b2, xsorted, weff, btot);
    knn_conv_kernel<<<dim3(B_ * (N_ / 64)), dim3(512), 0, stream>>>(
        xsorted, W1, weff, btot, out);
}